// Round 13
// baseline (7256.665 us; speedup 1.0000x reference)
//
#include <hip/hip_runtime.h>
#include <hip/hip_bf16.h>
#include <stdint.h>

#define HW      64
#define CIN     512
#define KOUT    512
#define BATCH   8
#define NANCH   9
#define NBOX    (HW*HW*NANCH)   /* 36864 */
#define PRE_NMS 6000
#define POST_NMS 300
#define SORT_N  8192

// ---------------------------------------------------------------------------
// Kernel 0: weight transpose  w[k][j] (j = ci*9+tap, 4608) -> wt[j][k]
// ---------------------------------------------------------------------------
__global__ __launch_bounds__(256)
void transpose_w(const float* __restrict__ w, float* __restrict__ wt) {
    __shared__ float t[32][33];
    const int jt = blockIdx.x * 32, kt = blockIdx.y * 32;
    const int c  = threadIdx.x & 31, r8 = threadIdx.x >> 5;
#pragma unroll
    for (int p = 0; p < 4; ++p) {
        int kl = r8 + p * 8;
        t[kl][c] = w[(size_t)(kt + kl) * 4608 + jt + c];
    }
    __syncthreads();
#pragma unroll
    for (int p = 0; p < 4; ++p) {
        int jl = r8 + p * 8;
        wt[(size_t)(jt + jl) * 512 + kt + c] = t[c][jl];
    }
}

// ---------------------------------------------------------------------------
// Kernel 1: 3x3 conv (pad=1) + bias + ReLU.  Structure = R12 (scalar-path
// weights, wave-uniform 16-k slice, lane = x, input-only dbuf LDS).
// Spill fixes (R13): (a) amdgpu_waves_per_eu(2,4) caps the occupancy target
// so the allocator may use up to 128 VGPRs (R11/R12: heuristic chose 24 and
// spilled acc -> 1.5 GB scratch traffic); (b) acc as 16 NAMED SCALARS (no
// array -> no alloca path).  Per-output FMA chain (ci_global asc, dy, dx,
// serial fp32 fmaf) BIT-IDENTICAL to all passing rounds.
// grid (8 ktiles, 64 rows, 8 b), block 256.
// ---------------------------------------------------------------------------
__global__
__attribute__((amdgpu_flat_work_group_size(256, 256)))
__attribute__((amdgpu_waves_per_eu(2, 4)))
void conv3x3_relu(const float* __restrict__ in, const float* __restrict__ wt,
                  const float* __restrict__ bias, float* __restrict__ feat) {
    __shared__ float s_in[2][8 * 3 * 68 + 4];   // 6544 B x 2; ring zeros permanent

    const int tid = threadIdx.x;
    const int k0  = blockIdx.x * 64;
    const int y   = blockIdx.y;
    const int b   = blockIdx.z;
    const int x   = tid & 63;                            // lane = x
    const int kw  = __builtin_amdgcn_readfirstlane(tid >> 6);  // wave-uniform 0..3
    const int kb  = k0 + kw * 16;

    // input staging: 2 float4 slots over 8ci x 3r x 16c4 (384)
    int in_lds[2]; int in_goff[2]; bool in_act[2], in_ok[2];
#pragma unroll
    for (int s = 0; s < 2; ++s) {
        int q   = tid + 256 * s;
        bool a  = (q < 384);
        int qq  = a ? q : 0;
        int ci  = qq / 48, rem = qq % 48;
        int r   = rem >> 4, c4 = rem & 15;
        int gy  = y - 1 + r;
        in_act[s] = a;
        in_ok[s]  = a && ((unsigned)gy < 64u);
        int gyc   = gy < 0 ? 0 : (gy > 63 ? 63 : gy);
        in_lds[s] = 4 + (ci * 3 + r) * 68 + 4 * c4;
        in_goff[s] = ((b * 512 + ci) * 64 + gyc) * 64 + 4 * c4;  // + cc8*32768
    }

    // zero input buffers once: establishes the permanent halo ring
    for (int i = tid; i < 2 * (8 * 3 * 68 + 4); i += 256) ((float*)s_in)[i] = 0.0f;
    __syncthreads();

    float4 pin[2];
    const float4 z4 = make_float4(0.f, 0.f, 0.f, 0.f);
    auto prefetch = [&](int cc8) {
#pragma unroll
        for (int s = 0; s < 2; ++s)
            pin[s] = in_ok[s] ? *(const float4*)&in[in_goff[s] + cc8 * 32768] : z4;
    };
    prefetch(0);

    float a00 = 0.f, a01 = 0.f, a02 = 0.f, a03 = 0.f;
    float a04 = 0.f, a05 = 0.f, a06 = 0.f, a07 = 0.f;
    float a08 = 0.f, a09 = 0.f, a10 = 0.f, a11 = 0.f;
    float a12 = 0.f, a13 = 0.f, a14 = 0.f, a15 = 0.f;

    for (int cc8 = 0; cc8 < 64; ++cc8) {
        float* SIN = &s_in[cc8 & 1][0];

#pragma unroll
        for (int s = 0; s < 2; ++s)
            if (in_act[s]) *(float4*)&SIN[in_lds[s]] = pin[s];
        __syncthreads();
        if (cc8 < 63) prefetch(cc8 + 1);

#pragma unroll
        for (int ci = 0; ci < 8; ++ci) {
#pragma unroll
            for (int dy = 0; dy < 3; ++dy) {
                const float* rp = &SIN[4 + (ci * 3 + dy) * 68];
                float iv0 = rp[x - 1];
                float iv1 = rp[x];
                float iv2 = rp[x + 1];
#pragma unroll
                for (int dx = 0; dx < 3; ++dx) {
                    const float* wp = &wt[(size_t)((cc8 * 8 + ci) * 9 + dy * 3 + dx) * 512 + kb];
                    float4 wA = *(const float4*)(wp);
                    float4 wB = *(const float4*)(wp + 4);
                    float4 wC = *(const float4*)(wp + 8);
                    float4 wD = *(const float4*)(wp + 12);
                    float f = (dx == 0) ? iv0 : (dx == 1) ? iv1 : iv2;
                    a00 = fmaf(f, wA.x, a00);
                    a01 = fmaf(f, wA.y, a01);
                    a02 = fmaf(f, wA.z, a02);
                    a03 = fmaf(f, wA.w, a03);
                    a04 = fmaf(f, wB.x, a04);
                    a05 = fmaf(f, wB.y, a05);
                    a06 = fmaf(f, wB.z, a06);
                    a07 = fmaf(f, wB.w, a07);
                    a08 = fmaf(f, wC.x, a08);
                    a09 = fmaf(f, wC.y, a09);
                    a10 = fmaf(f, wC.z, a10);
                    a11 = fmaf(f, wC.w, a11);
                    a12 = fmaf(f, wD.x, a12);
                    a13 = fmaf(f, wD.y, a13);
                    a14 = fmaf(f, wD.z, a14);
                    a15 = fmaf(f, wD.w, a15);
                }
            }
        }
    }
    // epilogue (cold): bias + relu + coalesced store
    float accv[16] = {a00, a01, a02, a03, a04, a05, a06, a07,
                      a08, a09, a10, a11, a12, a13, a14, a15};
#pragma unroll
    for (int k = 0; k < 16; ++k) {
        float v = fmaxf(accv[k] + bias[kb + k], 0.0f);
        feat[(((size_t)b * KOUT + kb + k) * HW + y) * HW + x] = v;
    }
}

// ---------------------------------------------------------------------------
// Kernel 2: 1x1 cls+reg heads + softmax + decode + clip + filter + key pack.
// (R12 verbatim)
// ---------------------------------------------------------------------------
__global__ __launch_bounds__(128, 2)
void heads(const float* __restrict__ feat,
           const float* __restrict__ wcls, const float* __restrict__ bcls,
           const float* __restrict__ wreg, const float* __restrict__ breg,
           const float* __restrict__ iminfo,
           unsigned long long* __restrict__ keys, float4* __restrict__ pbox) {
    __shared__ float s_w[128 * 56];

    const int tid = threadIdx.x;
    const int pix = blockIdx.x * 128 + tid;
    const int b   = pix >> 12;
    const int rem = pix & 4095;
    const int y   = rem >> 6;
    const int x   = rem & 63;

    float acc[54];
#pragma unroll
    for (int j = 0; j < 54; ++j) acc[j] = 0.0f;

    for (int cc = 0; cc < 512; cc += 128) {
        __syncthreads();
        for (int i = tid; i < 128 * 56; i += 128) {
            int cl = i / 56; int j = i % 56;
            float v = 0.0f;
            if (j < 18)      v = wcls[(size_t)j * 512 + cc + cl];
            else if (j < 54) v = wreg[(size_t)(j - 18) * 512 + cc + cl];
            s_w[i] = v;
        }
        __syncthreads();
#pragma unroll 4
        for (int c2 = 0; c2 < 128; ++c2) {
            float f = feat[(((size_t)b * 512 + cc + c2) * 64 + y) * 64 + x];
            const float* wr = &s_w[c2 * 56];
#pragma unroll
            for (int j4 = 0; j4 < 13; ++j4) {
                float4 w4 = *(const float4*)&wr[4 * j4];
                acc[4 * j4 + 0] = fmaf(f, w4.x, acc[4 * j4 + 0]);
                acc[4 * j4 + 1] = fmaf(f, w4.y, acc[4 * j4 + 1]);
                acc[4 * j4 + 2] = fmaf(f, w4.z, acc[4 * j4 + 2]);
                acc[4 * j4 + 3] = fmaf(f, w4.w, acc[4 * j4 + 3]);
            }
            float4 wt4 = *(const float4*)&wr[52];
            acc[52] = fmaf(f, wt4.x, acc[52]);
            acc[53] = fmaf(f, wt4.y, acc[53]);
        }
    }

    const float im_h = iminfo[b * 3 + 0];
    const float im_w = iminfo[b * 3 + 1];
    const float ms   = 16.0f * iminfo[b * 3 + 2];
    const float ASP[3] = {0.5f, 1.0f, 2.0f};
    const float SCL[3] = {8.0f, 16.0f, 32.0f};

#pragma unroll
    for (int a = 0; a < 9; ++a) {
        float c0 = acc[2 * a]     + bcls[2 * a];
        float c1 = acc[2 * a + 1] + bcls[2 * a + 1];
        float m  = fmaxf(c0, c1);
        float e0 = expf(c0 - m), e1 = expf(c1 - m);
        float fg = e1 / (e0 + e1);

        float d0 = acc[18 + 4 * a + 0] + breg[4 * a + 0];
        float d1 = acc[18 + 4 * a + 1] + breg[4 * a + 1];
        float d2 = acc[18 + 4 * a + 2] + breg[4 * a + 2];
        float d3 = acc[18 + 4 * a + 3] + breg[4 * a + 3];

        int ai = a / 3, si = a % 3;
        float wsz = sqrtf(256.0f / ASP[ai]) * SCL[si];
        float hsz = sqrtf(256.0f * ASP[ai]) * SCL[si];
        float sx = (float)x * 16.0f, sy = (float)y * 16.0f;
        float x1a = sx + (7.5f - 0.5f * (wsz - 1.0f));
        float y1a = sy + (7.5f - 0.5f * (hsz - 1.0f));
        float x2a = sx + (7.5f + 0.5f * (wsz - 1.0f));
        float y2a = sy + (7.5f + 0.5f * (hsz - 1.0f));

        float wa = x2a - x1a + 1.0f, ha = y2a - y1a + 1.0f;
        float cxa = x1a + 0.5f * wa, cya = y1a + 0.5f * ha;
        float cx = d0 * wa + cxa, cy = d1 * ha + cya;
        float pw = expf(d2) * wa, ph = expf(d3) * ha;
        float bx1 = cx - 0.5f * pw, by1 = cy - 0.5f * ph;
        float bx2 = cx + 0.5f * pw, by2 = cy + 0.5f * ph;

        bx1 = fminf(fmaxf(bx1, 0.0f), im_w - 1.0f);
        by1 = fminf(fmaxf(by1, 0.0f), im_h - 1.0f);
        bx2 = fminf(fmaxf(bx2, 0.0f), im_w - 1.0f);
        by2 = fminf(fmaxf(by2, 0.0f), im_h - 1.0f);

        bool ok = (bx2 - bx1 + 1.0f >= ms) && (by2 - by1 + 1.0f >= ms);
        float s = ok ? fg : -1e9f;

        unsigned u = __float_as_uint(s);
        u = (u & 0x80000000u) ? ~u : (u | 0x80000000u);
        int idx = (y * 64 + x) * 9 + a;
        keys[(size_t)b * NBOX + idx] =
            ((unsigned long long)u << 32) | (unsigned)(~(unsigned)idx);
        pbox[(size_t)b * NBOX + idx] = make_float4(bx1, by1, bx2, by2);
    }
}

// ---------------------------------------------------------------------------
// Kernel 3: per-batch top-6000 via radix select + LDS bitonic sort. (R1)
// ---------------------------------------------------------------------------
__global__ __launch_bounds__(1024)
void select_sort(const unsigned long long* __restrict__ keys,
                 const float4* __restrict__ pbox,
                 float4* __restrict__ sorted) {
    __shared__ unsigned long long sbuf[SORT_N];
    __shared__ unsigned hist[16][256];
    __shared__ unsigned sh_prefix, sh_remaining, sh_counter;

    const int tid = threadIdx.x;
    const int b   = blockIdx.x;
    const int wv  = tid >> 6;
    const unsigned long long* kb = keys + (size_t)b * NBOX;

    if (tid == 0) { sh_prefix = 0u; sh_remaining = PRE_NMS; sh_counter = 0u; }

    for (int p = 3; p >= 0; --p) {
        for (int i = tid; i < 16 * 256; i += 1024) ((unsigned*)hist)[i] = 0u;
        __syncthreads();
        unsigned prefix = sh_prefix;
        unsigned pmask  = (p == 3) ? 0u : (0xFFFFFFFFu << (8 * (p + 1)));
        for (int i = tid; i < NBOX; i += 1024) {
            unsigned u = (unsigned)(kb[i] >> 32);
            if ((u & pmask) == prefix)
                atomicAdd(&hist[wv][(u >> (8 * p)) & 255], 1u);
        }
        __syncthreads();
        if (tid < 256) {
            unsigned s = 0;
#pragma unroll
            for (int w2 = 0; w2 < 16; ++w2) s += hist[w2][tid];
            hist[0][tid] = s;
        }
        __syncthreads();
        if (tid == 0) {
            unsigned rem = sh_remaining;
            int v = 255;
            for (; v > 0; --v) {
                unsigned c = hist[0][v];
                if (rem <= c) break;
                rem -= c;
            }
            sh_prefix    = prefix | ((unsigned)v << (8 * p));
            sh_remaining = rem;
        }
        __syncthreads();
    }
    const unsigned thr = sh_prefix;

    for (int i = tid; i < NBOX; i += 1024) {
        unsigned long long k = kb[i];
        bool act = ((unsigned)(k >> 32) >= thr);
        unsigned long long bal = __ballot(act);
        if (act) {
            int lane   = tid & 63;
            int leader = __ffsll(bal) - 1;
            unsigned base = 0;
            if (lane == leader) base = atomicAdd(&sh_counter, (unsigned)__popcll(bal));
            base = __shfl(base, leader);
            unsigned off = (unsigned)__popcll(bal & ((1ull << lane) - 1ull));
            unsigned pos2 = base + off;
            if (pos2 < SORT_N) sbuf[pos2] = k;
        }
    }
    __syncthreads();
    unsigned n = sh_counter; if (n > SORT_N) n = SORT_N;
    for (int i = (int)n + tid; i < SORT_N; i += 1024) sbuf[i] = 0ull;
    __syncthreads();

    for (int k = 2; k <= SORT_N; k <<= 1) {
        for (int j = k >> 1; j > 0; j >>= 1) {
            for (int t = tid; t < SORT_N / 2; t += 1024) {
                int i  = ((t & ~(j - 1)) << 1) | (t & (j - 1));
                int ix = i | j;
                bool up = ((i & k) == 0);
                unsigned long long a = sbuf[i], c = sbuf[ix];
                bool sw = up ? (a < c) : (a > c);
                if (sw) { sbuf[i] = c; sbuf[ix] = a; }
            }
            __syncthreads();
        }
    }

    for (int i = tid; i < PRE_NMS; i += 1024) {
        unsigned idx = ~((unsigned)sbuf[i]);
        sorted[(size_t)b * PRE_NMS + i] = pbox[(size_t)b * NBOX + idx];
    }
}

// ---------------------------------------------------------------------------
// Kernel 4: greedy NMS — single 64-lane wave per batch, ZERO barriers in the
// pick loop.  Validity bits in registers: lane owns boxes i = s*64+lane,
// s = 0..93 (u64 m0 for s<64, u32 m1 for s 64..93; i<6000 enforced at init).
// argmax over valid scores == min valid index (input sorted desc, unique):
// per-lane ffs -> 6-step shfl_xor min.  Suppression iterates SET bits only;
// boxes in padded LDS [94][65] float4 ((s+lane)%8 bank spread).  IoU formula
// per pair bit-identical to the R1-proven version; empty -> j=0; chosen box
// self-suppresses via IoU=1.  grid (8), block 64.
// ---------------------------------------------------------------------------
__global__ __launch_bounds__(64)
void nms(const float4* __restrict__ sorted, float* __restrict__ out) {
    __shared__ float4 sbx[94 * 65];   // 97,760 B

    const int lane = threadIdx.x;
    const int b    = blockIdx.x;
    const float4* sb = sorted + (size_t)b * PRE_NMS;

    for (int i = lane; i < PRE_NMS; i += 64)
        sbx[(i >> 6) * 65 + (i & 63)] = sb[i];
    __syncthreads();

    unsigned long long m0 = ~0ull;                          // s = 0..63
    unsigned           m1 = (lane < 48) ? 0x3FFFFFFFu       // s = 64..93
                                        : 0x1FFFFFFFu;      // s=93 only if lane<48

    for (int it = 0; it < POST_NMS; ++it) {
        int cand;
        if (m0)      cand = (__ffsll(m0) - 1) * 64 + lane;
        else if (m1) cand = (64 + __ffs(m1) - 1) * 64 + lane;
        else         cand = 0x7FFFFFFF;
#pragma unroll
        for (int off = 32; off > 0; off >>= 1) {
            int o = __shfl_xor(cand, off);
            cand = (o < cand) ? o : cand;
        }
        int j = (cand == 0x7FFFFFFF) ? 0 : cand;
        float4 jb = sbx[(j >> 6) * 65 + (j & 63)];   // uniform -> broadcast
        if (lane == 0) {
            float* o = out + ((size_t)b * POST_NMS + it) * 5;
            o[0] = (float)b; o[1] = jb.x; o[2] = jb.y; o[3] = jb.z; o[4] = jb.w;
        }
        float ja = (jb.z - jb.x + 1.0f) * (jb.w - jb.y + 1.0f);

        unsigned long long t0 = m0;
        while (t0) {
            int s = __ffsll(t0) - 1; t0 &= t0 - 1;
            float4 v = sbx[s * 65 + lane];
            float xx1 = fmaxf(jb.x, v.x);
            float yy1 = fmaxf(jb.y, v.y);
            float xx2 = fminf(jb.z, v.z);
            float yy2 = fminf(jb.w, v.w);
            float inter = fmaxf(0.0f, xx2 - xx1 + 1.0f) *
                          fmaxf(0.0f, yy2 - yy1 + 1.0f);
            float ar = (v.z - v.x + 1.0f) * (v.w - v.y + 1.0f);
            float iou = inter / (ja + ar - inter);
            if (iou > 0.7f) m0 &= ~(1ull << s);
        }
        unsigned t1 = m1;
        while (t1) {
            int s = __ffs(t1) - 1; t1 &= t1 - 1;
            float4 v = sbx[(64 + s) * 65 + lane];
            float xx1 = fmaxf(jb.x, v.x);
            float yy1 = fmaxf(jb.y, v.y);
            float xx2 = fminf(jb.z, v.z);
            float yy2 = fminf(jb.w, v.w);
            float inter = fmaxf(0.0f, xx2 - xx1 + 1.0f) *
                          fmaxf(0.0f, yy2 - yy1 + 1.0f);
            float ar = (v.z - v.x + 1.0f) * (v.w - v.y + 1.0f);
            float iou = inter / (ja + ar - inter);
            if (iou > 0.7f) m1 &= ~(1u << s);
        }
    }
}

// ---------------------------------------------------------------------------
extern "C" void kernel_launch(void* const* d_in, const int* in_sizes, int n_in,
                              void* d_out, int out_size, void* d_ws, size_t ws_size,
                              hipStream_t stream) {
    (void)in_sizes; (void)n_in; (void)out_size; (void)ws_size;
    const float* input  = (const float*)d_in[0];
    // d_in[1] = gt_box (unused)
    const float* iminfo = (const float*)d_in[2];
    const float* wfeat  = (const float*)d_in[3];
    const float* bfeat  = (const float*)d_in[4];
    const float* wcls   = (const float*)d_in[5];
    const float* bcls   = (const float*)d_in[6];
    const float* wreg   = (const float*)d_in[7];
    const float* breg   = (const float*)d_in[8];
    float* out = (float*)d_out;

    char* ws = (char*)d_ws;
    // layout: feat [0, 67.1MB); wt (9.44MB) aliases keys/pbox/sorted region:
    //   wt is dead after conv; keys/pbox/sorted written only after conv.
    float*               feat   = (float*)ws;                                   // 67108864 B
    float*               wt     = (float*)(ws + 67108864);                      //  9437184 B (dead after conv)
    unsigned long long*  keys   = (unsigned long long*)(ws + 67108864);         //  2359296 B
    float4*              pbox   = (float4*)(ws + 67108864 + 2359296);           //  4718592 B
    float4*              sorted = (float4*)(ws + 67108864 + 2359296 + 4718592); //   768000 B

    transpose_w<<<dim3(144, 16), 256, 0, stream>>>(wfeat, wt);
    conv3x3_relu<<<dim3(8, 64, 8), 256, 0, stream>>>(input, wt, bfeat, feat);
    heads<<<dim3(256), 128, 0, stream>>>(feat, wcls, bcls, wreg, breg, iminfo, keys, pbox);
    select_sort<<<dim3(8), 1024, 0, stream>>>(keys, pbox, sorted);
    nms<<<dim3(8), 64, 0, stream>>>(sorted, out);
}